// Round 1
// baseline (830.913 us; speedup 1.0000x reference)
//
#include <hip/hip_runtime.h>

#define NEG_SLOPE 0.2f

__device__ __forceinline__ float elu_f(float x) {
    return x > 0.f ? x : __expf(x) - 1.f;
}

// ---------------------------------------------------------------------------
// GEMM1: h1 = x @ W1  ([N,64] x [64,64]) with fused alpha_src1/alpha_dst1
// block = 256 threads = 4 rows x 64 cols; each wave holds one full row.
// ---------------------------------------------------------------------------
__global__ __launch_bounds__(256) void gemm1_kernel(
    const float* __restrict__ x, const float* __restrict__ W,
    const float* __restrict__ a_src, const float* __restrict__ a_dst,
    float* __restrict__ h1, float* __restrict__ as1, float* __restrict__ ad1,
    int N)
{
    __shared__ float Wl[64 * 64];
    __shared__ float Xl[4][64];
    int tid = threadIdx.x;
    for (int i = tid; i < 64 * 64; i += 256) Wl[i] = W[i];
    int r   = tid >> 6;   // 0..3 (wave id)
    int col = tid & 63;
    int row = blockIdx.x * 4 + r;
    if (row < N) Xl[r][col] = x[(size_t)row * 64 + col];
    __syncthreads();
    if (row >= N) return;

    float acc = 0.f;
#pragma unroll
    for (int k = 0; k < 64; ++k) acc += Xl[r][k] * Wl[k * 64 + col];
    h1[(size_t)row * 64 + col] = acc;

    // alpha_s[n,h] = sum_d h[n,h,d]*a_src[h,d]; a_src flat index == col
    int head = col >> 5;
    float ps = acc * a_src[col];
    float pd = acc * a_dst[col];
#pragma unroll
    for (int off = 16; off; off >>= 1) {
        ps += __shfl_xor(ps, off, 32);
        pd += __shfl_xor(pd, off, 32);
    }
    if ((col & 31) == 0) {
        as1[row * 2 + head] = ps;
        ad1[row * 2 + head] = pd;
    }
}

// ---------------------------------------------------------------------------
// Edge pass layer 1: 64 lanes per edge (incl. self-loops appended at end).
// w = exp(leaky_relu(as[src]+ad[dst]))  (no max-subtraction: values are small)
// acc1[dst,:] += w * h1[src,:]; den1[dst,h] += w
// ---------------------------------------------------------------------------
__global__ __launch_bounds__(256) void edge1_kernel(
    const int* __restrict__ ei, const float* __restrict__ h1,
    const float* __restrict__ as1, const float* __restrict__ ad1,
    float* __restrict__ acc1, float* __restrict__ den1, int E, int N)
{
    unsigned t = blockIdx.x * 256u + threadIdx.x;
    int edge = (int)(t >> 6);
    int elem = (int)(t & 63u);
    if (edge >= E + N) return;
    int src, dst;
    if (edge < E) { src = ei[edge]; dst = ei[E + edge]; }
    else          { src = dst = edge - E; }
    int head = elem >> 5;
    float e = as1[src * 2 + head] + ad1[dst * 2 + head];
    e = e > 0.f ? e : NEG_SLOPE * e;
    float w = __expf(e);
    atomicAdd(&acc1[(size_t)dst * 64 + elem], w * h1[(size_t)src * 64 + elem]);
    if ((elem & 31) == 0) atomicAdd(&den1[dst * 2 + head], w);
}

// ---------------------------------------------------------------------------
// Normalize + bias + ELU -> h1e (aliases h1 storage)
// ---------------------------------------------------------------------------
__global__ __launch_bounds__(256) void norm1_kernel(
    const float* __restrict__ acc1, const float* __restrict__ den1,
    const float* __restrict__ b1, float* __restrict__ h1e, int N)
{
    unsigned t = blockIdx.x * 256u + threadIdx.x;
    if (t >= (unsigned)N * 64u) return;
    int n = t >> 6, elem = t & 63;
    float v = acc1[t] / den1[n * 2 + (elem >> 5)] + b1[elem];
    h1e[t] = elu_f(v);
}

// ---------------------------------------------------------------------------
// GEMM2: h2 = h1e @ W2 ([N,64] x [64,32]) with fused alpha2 reductions
// block = 256 threads = 8 rows x 32 cols
// ---------------------------------------------------------------------------
__global__ __launch_bounds__(256) void gemm2_kernel(
    const float* __restrict__ xin, const float* __restrict__ W,
    const float* __restrict__ a_src, const float* __restrict__ a_dst,
    float* __restrict__ h2, float* __restrict__ as2, float* __restrict__ ad2,
    int N)
{
    __shared__ float Wl[64 * 32];
    __shared__ float Xl[8][64];
    int tid = threadIdx.x;
    for (int i = tid; i < 64 * 32; i += 256) Wl[i] = W[i];
    int base = blockIdx.x * 8;
    for (int i = tid; i < 8 * 64; i += 256) {
        int rr = i >> 6, cc = i & 63;
        if (base + rr < N) Xl[rr][cc] = xin[(size_t)(base + rr) * 64 + cc];
    }
    __syncthreads();
    int r   = tid >> 5;   // 0..7
    int col = tid & 31;
    int row = base + r;
    if (row >= N) return;

    float acc = 0.f;
#pragma unroll
    for (int k = 0; k < 64; ++k) acc += Xl[r][k] * Wl[k * 32 + col];
    h2[(size_t)row * 32 + col] = acc;

    float ps = acc * a_src[col];
    float pd = acc * a_dst[col];
#pragma unroll
    for (int off = 16; off; off >>= 1) {
        ps += __shfl_xor(ps, off, 32);
        pd += __shfl_xor(pd, off, 32);
    }
    if (col == 0) { as2[row] = ps; ad2[row] = pd; }
}

// ---------------------------------------------------------------------------
// Edge pass layer 2: 32 lanes per edge (H=1, D=32)
// ---------------------------------------------------------------------------
__global__ __launch_bounds__(256) void edge2_kernel(
    const int* __restrict__ ei, const float* __restrict__ h2,
    const float* __restrict__ as2, const float* __restrict__ ad2,
    float* __restrict__ acc2, float* __restrict__ den2, int E, int N)
{
    unsigned t = blockIdx.x * 256u + threadIdx.x;
    int edge = (int)(t >> 5);
    int elem = (int)(t & 31u);
    if (edge >= E + N) return;
    int src, dst;
    if (edge < E) { src = ei[edge]; dst = ei[E + edge]; }
    else          { src = dst = edge - E; }
    float e = as2[src] + ad2[dst];
    e = e > 0.f ? e : NEG_SLOPE * e;
    float w = __expf(e);
    atomicAdd(&acc2[(size_t)dst * 32 + elem], w * h2[(size_t)src * 32 + elem]);
    if (elem == 0) atomicAdd(&den2[dst], w);
}

// ---------------------------------------------------------------------------
// Final: normalize + b2 + ELU -> h out; score = h_elu @ fcW + fcb
// out layout: [0,N) scores, [N, N+N*32) h
// ---------------------------------------------------------------------------
__global__ __launch_bounds__(256) void final_kernel(
    const float* __restrict__ acc2, const float* __restrict__ den2,
    const float* __restrict__ b2, const float* __restrict__ fcW,
    const float* __restrict__ fcb, float* __restrict__ out, int N)
{
    unsigned t = blockIdx.x * 256u + threadIdx.x;
    if (t >= (unsigned)N * 32u) return;
    int n = t >> 5, elem = t & 31;
    float v = acc2[t] / den2[n] + b2[elem];
    v = elu_f(v);
    out[(size_t)N + (size_t)n * 32 + elem] = v;
    float p = v * fcW[elem];
#pragma unroll
    for (int off = 16; off; off >>= 1) p += __shfl_xor(p, off, 32);
    if (elem == 0) out[n] = p + fcb[0];
}

extern "C" void kernel_launch(void* const* d_in, const int* in_sizes, int n_in,
                              void* d_out, int out_size, void* d_ws, size_t ws_size,
                              hipStream_t stream) {
    const float* x    = (const float*)d_in[0];
    const int*   ei   = (const int*)d_in[1];
    const float* W1   = (const float*)d_in[2];
    const float* a_s1 = (const float*)d_in[3];
    const float* a_d1 = (const float*)d_in[4];
    const float* b1   = (const float*)d_in[5];
    const float* W2   = (const float*)d_in[6];
    const float* a_s2 = (const float*)d_in[7];
    const float* a_d2 = (const float*)d_in[8];
    const float* b2   = (const float*)d_in[9];
    const float* fcW  = (const float*)d_in[10];
    const float* fcb  = (const float*)d_in[11];

    const int N = in_sizes[0] / 64;
    const int E = in_sizes[1] / 2;

    float* ws   = (float*)d_ws;
    float* h1   = ws;                       // N*64 (reused as h1e after edge1)
    float* as1  = h1   + (size_t)N * 64;    // N*2
    float* ad1  = as1  + (size_t)N * 2;     // N*2
    float* den1 = ad1  + (size_t)N * 2;     // N*2
    float* acc1 = den1 + (size_t)N * 2;     // N*64
    float* h2   = acc1 + (size_t)N * 64;    // N*32
    float* as2  = h2   + (size_t)N * 32;    // N
    float* ad2  = as2  + (size_t)N;         // N
    float* den2 = ad2  + (size_t)N;         // N
    float* acc2 = den2 + (size_t)N;         // N*32
    float* h1e  = h1;                       // alias: h1 dead after edge1

    hipMemsetAsync(den1, 0, sizeof(float) * (size_t)N * 2, stream);
    hipMemsetAsync(acc1, 0, sizeof(float) * (size_t)N * 64, stream);
    hipMemsetAsync(den2, 0, sizeof(float) * (size_t)N, stream);
    hipMemsetAsync(acc2, 0, sizeof(float) * (size_t)N * 32, stream);

    gemm1_kernel<<<(N + 3) / 4, 256, 0, stream>>>(x, W1, a_s1, a_d1, h1, as1, ad1, N);

    {
        size_t threads = (size_t)(E + N) * 64;
        edge1_kernel<<<(unsigned)((threads + 255) / 256), 256, 0, stream>>>(
            ei, h1, as1, ad1, acc1, den1, E, N);
    }

    norm1_kernel<<<((size_t)N * 64 + 255) / 256, 256, 0, stream>>>(acc1, den1, b1, h1e, N);

    gemm2_kernel<<<(N + 7) / 8, 256, 0, stream>>>(h1e, W2, a_s2, a_d2, h2, as2, ad2, N);

    {
        size_t threads = (size_t)(E + N) * 32;
        edge2_kernel<<<(unsigned)((threads + 255) / 256), 256, 0, stream>>>(
            ei, h2, as2, ad2, acc2, den2, E, N);
    }

    final_kernel<<<((size_t)N * 32 + 255) / 256, 256, 0, stream>>>(
        acc2, den2, b2, fcW, fcb, (float*)d_out, N);
}

// Round 2
// 578.146 us; speedup vs baseline: 1.4372x; 1.4372x over previous
//
#include <hip/hip_runtime.h>

#define NEG_SLOPE 0.2f

__device__ __forceinline__ float elu_f(float x) {
    return x > 0.f ? x : __expf(x) - 1.f;
}
__device__ __forceinline__ float lrelu_f(float x) {
    return x > 0.f ? x : NEG_SLOPE * x;
}

// ---------------------------------------------------------------------------
// CSR build step 1: histogram of destination nodes (real edges only;
// self-loops are folded analytically into the aggregation kernels).
// ---------------------------------------------------------------------------
__global__ __launch_bounds__(256) void hist_kernel(
    const int* __restrict__ ei, int* __restrict__ cnt, int E)
{
    int t = blockIdx.x * 256 + threadIdx.x;
    if (t < E) atomicAdd(&cnt[ei[E + t]], 1);
}

// ---------------------------------------------------------------------------
// CSR build step 2: single-block exclusive scan over N counts.
// Writes rowptr[0..N] and resets cnt[] to the start offsets (scatter cursors).
// ---------------------------------------------------------------------------
__global__ __launch_bounds__(1024) void scan_kernel(
    int* __restrict__ cnt, int* __restrict__ rowptr, int N)
{
    __shared__ int part[1024];
    int t = threadIdx.x;
    int C = (N + 1023) / 1024;
    int begin = t * C;
    int end = begin + C; if (end > N) end = N;
    int s = 0;
    for (int i = begin; i < end; ++i) s += cnt[i];
    part[t] = s;
    __syncthreads();
    // Hillis-Steele inclusive scan
    for (int off = 1; off < 1024; off <<= 1) {
        int v = (t >= off) ? part[t - off] : 0;
        __syncthreads();
        part[t] += v;
        __syncthreads();
    }
    int run = (t == 0) ? 0 : part[t - 1];
    for (int i = begin; i < end; ++i) {
        int c = cnt[i];
        rowptr[i] = run;
        cnt[i] = run;      // becomes the scatter cursor
        run += c;
    }
    if (t == 0) rowptr[N] = part[1023];
}

// ---------------------------------------------------------------------------
// CSR build step 3: scatter src indices grouped by dst.
// ---------------------------------------------------------------------------
__global__ __launch_bounds__(256) void scatter_kernel(
    const int* __restrict__ ei, int* __restrict__ cursor,
    int* __restrict__ srclist, int E)
{
    int t = blockIdx.x * 256 + threadIdx.x;
    if (t >= E) return;
    int src = ei[t], dst = ei[E + t];
    int pos = atomicAdd(&cursor[dst], 1);
    srclist[pos] = src;
}

// ---------------------------------------------------------------------------
// GEMM1: h1 = x @ W1  ([N,64] x [64,64]) with fused alpha_src1/alpha_dst1
// ---------------------------------------------------------------------------
__global__ __launch_bounds__(256) void gemm1_kernel(
    const float* __restrict__ x, const float* __restrict__ W,
    const float* __restrict__ a_src, const float* __restrict__ a_dst,
    float* __restrict__ h1, float* __restrict__ as1, float* __restrict__ ad1,
    int N)
{
    __shared__ float Wl[64 * 64];
    __shared__ float Xl[4][64];
    int tid = threadIdx.x;
    for (int i = tid; i < 64 * 64; i += 256) Wl[i] = W[i];
    int r   = tid >> 6;
    int col = tid & 63;
    int row = blockIdx.x * 4 + r;
    if (row < N) Xl[r][col] = x[(size_t)row * 64 + col];
    __syncthreads();
    if (row >= N) return;

    float acc = 0.f;
#pragma unroll
    for (int k = 0; k < 64; ++k) acc += Xl[r][k] * Wl[k * 64 + col];
    h1[(size_t)row * 64 + col] = acc;

    int head = col >> 5;
    float ps = acc * a_src[col];
    float pd = acc * a_dst[col];
#pragma unroll
    for (int off = 16; off; off >>= 1) {
        ps += __shfl_xor(ps, off, 32);
        pd += __shfl_xor(pd, off, 32);
    }
    if ((col & 31) == 0) {
        as1[row * 2 + head] = ps;
        ad1[row * 2 + head] = pd;
    }
}

// ---------------------------------------------------------------------------
// Layer-1 aggregation, gather-side: one 64-lane wave per dst node.
// Registers accumulate sum_w and sum(w*h1[src,:]); one 256 B write per node.
// Fuses softmax-normalize + bias + ELU (old norm1_kernel).
// ---------------------------------------------------------------------------
__global__ __launch_bounds__(256) void agg1_kernel(
    const int* __restrict__ rowptr, const int* __restrict__ srclist,
    const float* __restrict__ h1, const float* __restrict__ as1,
    const float* __restrict__ ad1, const float* __restrict__ b1,
    float* __restrict__ h1e, int N)
{
    int n = (blockIdx.x * 256 + threadIdx.x) >> 6;
    int lane = threadIdx.x & 63;
    if (n >= N) return;
    int head = lane >> 5;
    float adn = ad1[n * 2 + head];

    // self-loop
    float w = __expf(lrelu_f(as1[n * 2 + head] + adn));
    float den = w;
    float acc = w * h1[(size_t)n * 64 + lane];

    int i = rowptr[n], endp = rowptr[n + 1];
    // 2x unrolled gather loop for latency overlap
    for (; i + 1 < endp; i += 2) {
        int s0 = srclist[i], s1 = srclist[i + 1];
        float w0 = __expf(lrelu_f(as1[s0 * 2 + head] + adn));
        float w1 = __expf(lrelu_f(as1[s1 * 2 + head] + adn));
        float g0 = h1[(size_t)s0 * 64 + lane];
        float g1 = h1[(size_t)s1 * 64 + lane];
        den += w0 + w1;
        acc += w0 * g0 + w1 * g1;
    }
    if (i < endp) {
        int s0 = srclist[i];
        float w0 = __expf(lrelu_f(as1[s0 * 2 + head] + adn));
        den += w0;
        acc += w0 * h1[(size_t)s0 * 64 + lane];
    }

    float v = acc / den + b1[lane];
    h1e[(size_t)n * 64 + lane] = elu_f(v);
}

// ---------------------------------------------------------------------------
// GEMM2: h2 = h1e @ W2 ([N,64] x [64,32]) with fused alpha2 reductions
// ---------------------------------------------------------------------------
__global__ __launch_bounds__(256) void gemm2_kernel(
    const float* __restrict__ xin, const float* __restrict__ W,
    const float* __restrict__ a_src, const float* __restrict__ a_dst,
    float* __restrict__ h2, float* __restrict__ as2, float* __restrict__ ad2,
    int N)
{
    __shared__ float Wl[64 * 32];
    __shared__ float Xl[8][64];
    int tid = threadIdx.x;
    for (int i = tid; i < 64 * 32; i += 256) Wl[i] = W[i];
    int base = blockIdx.x * 8;
    for (int i = tid; i < 8 * 64; i += 256) {
        int rr = i >> 6, cc = i & 63;
        if (base + rr < N) Xl[rr][cc] = xin[(size_t)(base + rr) * 64 + cc];
    }
    __syncthreads();
    int r   = tid >> 5;
    int col = tid & 31;
    int row = base + r;
    if (row >= N) return;

    float acc = 0.f;
#pragma unroll
    for (int k = 0; k < 64; ++k) acc += Xl[r][k] * Wl[k * 32 + col];
    h2[(size_t)row * 32 + col] = acc;

    float ps = acc * a_src[col];
    float pd = acc * a_dst[col];
#pragma unroll
    for (int off = 16; off; off >>= 1) {
        ps += __shfl_xor(ps, off, 32);
        pd += __shfl_xor(pd, off, 32);
    }
    if (col == 0) { as2[row] = ps; ad2[row] = pd; }
}

// ---------------------------------------------------------------------------
// Layer-2 aggregation, gather-side: 32 lanes per dst node.
// Fuses normalize + b2 + ELU + FC score (old final_kernel).
// out layout: [0,N) scores, [N, N+N*32) h
// ---------------------------------------------------------------------------
__global__ __launch_bounds__(256) void agg2_kernel(
    const int* __restrict__ rowptr, const int* __restrict__ srclist,
    const float* __restrict__ h2, const float* __restrict__ as2,
    const float* __restrict__ ad2, const float* __restrict__ b2,
    const float* __restrict__ fcW, const float* __restrict__ fcb,
    float* __restrict__ out, int N)
{
    int g = blockIdx.x * 256 + threadIdx.x;
    int n = g >> 5;
    int lane = g & 31;
    if (n >= N) return;
    float adn = ad2[n];

    float w = __expf(lrelu_f(as2[n] + adn));
    float den = w;
    float acc = w * h2[(size_t)n * 32 + lane];

    int i = rowptr[n], endp = rowptr[n + 1];
    for (; i + 1 < endp; i += 2) {
        int s0 = srclist[i], s1 = srclist[i + 1];
        float w0 = __expf(lrelu_f(as2[s0] + adn));
        float w1 = __expf(lrelu_f(as2[s1] + adn));
        float g0 = h2[(size_t)s0 * 32 + lane];
        float g1 = h2[(size_t)s1 * 32 + lane];
        den += w0 + w1;
        acc += w0 * g0 + w1 * g1;
    }
    if (i < endp) {
        int s0 = srclist[i];
        float w0 = __expf(lrelu_f(as2[s0] + adn));
        den += w0;
        acc += w0 * h2[(size_t)s0 * 32 + lane];
    }

    float v = elu_f(acc / den + b2[lane]);
    out[(size_t)N + (size_t)n * 32 + lane] = v;
    float p = v * fcW[lane];
#pragma unroll
    for (int off = 16; off; off >>= 1) p += __shfl_xor(p, off, 32);
    if (lane == 0) out[n] = p + fcb[0];
}

extern "C" void kernel_launch(void* const* d_in, const int* in_sizes, int n_in,
                              void* d_out, int out_size, void* d_ws, size_t ws_size,
                              hipStream_t stream) {
    const float* x    = (const float*)d_in[0];
    const int*   ei   = (const int*)d_in[1];
    const float* W1   = (const float*)d_in[2];
    const float* a_s1 = (const float*)d_in[3];
    const float* a_d1 = (const float*)d_in[4];
    const float* b1   = (const float*)d_in[5];
    const float* W2   = (const float*)d_in[6];
    const float* a_s2 = (const float*)d_in[7];
    const float* a_d2 = (const float*)d_in[8];
    const float* b2   = (const float*)d_in[9];
    const float* fcW  = (const float*)d_in[10];
    const float* fcb  = (const float*)d_in[11];

    const int N = in_sizes[0] / 64;
    const int E = in_sizes[1] / 2;

    // Workspace layout (floats then ints).
    float* fws  = (float*)d_ws;
    float* h1   = fws;                      // N*64  (reused as h2 after agg1)
    float* h1e  = h1   + (size_t)N * 64;    // N*64
    float* as1  = h1e  + (size_t)N * 64;    // N*2
    float* ad1  = as1  + (size_t)N * 2;     // N*2
    float* as2  = ad1  + (size_t)N * 2;     // N
    float* ad2  = as2  + (size_t)N;         // N
    int*   cnt     = (int*)(ad2 + (size_t)N);  // N   (histogram, then cursor)
    int*   rowptr  = cnt + N;                  // N+1
    int*   srclist = rowptr + N + 1;           // E
    float* h2   = h1;                      // alias: h1 dead after agg1

    hipMemsetAsync(cnt, 0, sizeof(int) * (size_t)N, stream);

    hist_kernel<<<(E + 255) / 256, 256, 0, stream>>>(ei, cnt, E);
    scan_kernel<<<1, 1024, 0, stream>>>(cnt, rowptr, N);
    scatter_kernel<<<(E + 255) / 256, 256, 0, stream>>>(ei, cnt, srclist, E);

    gemm1_kernel<<<(N + 3) / 4, 256, 0, stream>>>(x, W1, a_s1, a_d1, h1, as1, ad1, N);

    agg1_kernel<<<((size_t)N * 64 + 255) / 256, 256, 0, stream>>>(
        rowptr, srclist, h1, as1, ad1, b1, h1e, N);

    gemm2_kernel<<<(N + 7) / 8, 256, 0, stream>>>(h1e, W2, a_s2, a_d2, h2, as2, ad2, N);

    agg2_kernel<<<((size_t)N * 32 + 255) / 256, 256, 0, stream>>>(
        rowptr, srclist, h2, as2, ad2, b2, fcW, fcb, (float*)d_out, N);
}

// Round 3
// 492.615 us; speedup vs baseline: 1.6867x; 1.1736x over previous
//
#include <hip/hip_runtime.h>

#define NEG_SLOPE 0.2f
#define NRANGE 8          // dst-range partitions == XCD count (b%8 heuristic)

__device__ __forceinline__ float elu_f(float x) {
    return x > 0.f ? x : __expf(x) - 1.f;
}
__device__ __forceinline__ float lrelu_f(float x) {
    return x > 0.f ? x : NEG_SLOPE * x;
}

// ---------------------------------------------------------------------------
// CSR build step 1: histogram of destination nodes (real edges only).
// Non-temporal reads: pure streaming, don't pollute L2.
// ---------------------------------------------------------------------------
__global__ __launch_bounds__(256) void hist_kernel(
    const int* __restrict__ ei, int* __restrict__ cnt, int E)
{
    int t = blockIdx.x * 256 + threadIdx.x;
    if (t < E) atomicAdd(&cnt[__builtin_nontemporal_load(&ei[E + t])], 1);
}

// ---------------------------------------------------------------------------
// CSR build step 2: single-block exclusive scan over N counts.
// Writes rowptr[0..N] and resets cnt[] to the start offsets (scatter cursors).
// ---------------------------------------------------------------------------
__global__ __launch_bounds__(1024) void scan_kernel(
    int* __restrict__ cnt, int* __restrict__ rowptr, int N)
{
    __shared__ int part[1024];
    int t = threadIdx.x;
    int C = (N + 1023) / 1024;
    int begin = t * C;
    int end = begin + C; if (end > N) end = N;
    int s = 0;
    for (int i = begin; i < end; ++i) s += cnt[i];
    part[t] = s;
    __syncthreads();
    for (int off = 1; off < 1024; off <<= 1) {
        int v = (t >= off) ? part[t - off] : 0;
        __syncthreads();
        part[t] += v;
        __syncthreads();
    }
    int run = (t == 0) ? 0 : part[t - 1];
    for (int i = begin; i < end; ++i) {
        int c = cnt[i];
        rowptr[i] = run;
        cnt[i] = run;      // becomes the scatter cursor
        run += c;
    }
    if (t == 0) rowptr[N] = part[1023];
}

// ---------------------------------------------------------------------------
// CSR build step 3: scatter src indices grouped by dst.
// Block b: dst range (b&7) [XCD-affine via round-robin dispatch], edge chunk
// b>>3. Each XCD's L2 then owns a ~0.8MB contiguous srclist slice and
// accumulates full 64B lines before writeback. ei reads are non-temporal so
// the stream doesn't evict the dirty scatter lines.
// ---------------------------------------------------------------------------
__global__ __launch_bounds__(256) void scatter_kernel(
    const int* __restrict__ ei, int* __restrict__ cursor,
    int* __restrict__ srclist, int E, int N, int nChunks)
{
    int b = blockIdx.x;
    int range = b & (NRANGE - 1);
    int chunk = b >> 3;
    int RS = (N + NRANGE - 1) / NRANGE;
    int lo = range * RS;
    int hi = lo + RS; if (hi > N) hi = N;
    int per = (E + nChunks - 1) / nChunks;
    int beg = chunk * per;
    int end = beg + per; if (end > E) end = E;
    for (int i = beg + (int)threadIdx.x; i < end; i += 256) {
        int dst = __builtin_nontemporal_load(&ei[E + i]);
        if (dst >= lo && dst < hi) {
            int src = __builtin_nontemporal_load(&ei[i]);
            int pos = atomicAdd(&cursor[dst], 1);
            srclist[pos] = src;
        }
    }
}

// ---------------------------------------------------------------------------
// GEMM1: h1 = x @ W1  ([N,64] x [64,64]) with fused alpha_src1/alpha_dst1
// ---------------------------------------------------------------------------
__global__ __launch_bounds__(256) void gemm1_kernel(
    const float* __restrict__ x, const float* __restrict__ W,
    const float* __restrict__ a_src, const float* __restrict__ a_dst,
    float* __restrict__ h1, float* __restrict__ as1, float* __restrict__ ad1,
    int N)
{
    __shared__ float Wl[64 * 64];
    __shared__ float Xl[4][64];
    int tid = threadIdx.x;
    for (int i = tid; i < 64 * 64; i += 256) Wl[i] = W[i];
    int r   = tid >> 6;
    int col = tid & 63;
    int row = blockIdx.x * 4 + r;
    if (row < N) Xl[r][col] = x[(size_t)row * 64 + col];
    __syncthreads();
    if (row >= N) return;

    float acc = 0.f;
#pragma unroll
    for (int k = 0; k < 64; ++k) acc += Xl[r][k] * Wl[k * 64 + col];
    h1[(size_t)row * 64 + col] = acc;

    int head = col >> 5;
    float ps = acc * a_src[col];
    float pd = acc * a_dst[col];
#pragma unroll
    for (int off = 16; off; off >>= 1) {
        ps += __shfl_xor(ps, off, 32);
        pd += __shfl_xor(pd, off, 32);
    }
    if ((col & 31) == 0) {
        as1[row * 2 + head] = ps;
        ad1[row * 2 + head] = pd;
    }
}

// ---------------------------------------------------------------------------
// Layer-1 aggregation, gather-side: one 64-lane wave per dst node.
// 4x unrolled: 4 srclist + 4 as1 + 4 h1-row gathers in flight per iter.
// ---------------------------------------------------------------------------
__global__ __launch_bounds__(256) void agg1_kernel(
    const int* __restrict__ rowptr, const int* __restrict__ srclist,
    const float* __restrict__ h1, const float* __restrict__ as1,
    const float* __restrict__ ad1, const float* __restrict__ b1,
    float* __restrict__ h1e, int N)
{
    int n = (blockIdx.x * 256 + threadIdx.x) >> 6;
    int lane = threadIdx.x & 63;
    if (n >= N) return;
    int head = lane >> 5;
    float adn = ad1[n * 2 + head];

    // self-loop
    float w = __expf(lrelu_f(as1[n * 2 + head] + adn));
    float den = w;
    float acc = w * h1[(size_t)n * 64 + lane];

    int i = rowptr[n], endp = rowptr[n + 1];
    for (; i + 3 < endp; i += 4) {
        int s0 = srclist[i], s1 = srclist[i + 1];
        int s2 = srclist[i + 2], s3 = srclist[i + 3];
        float a0 = as1[s0 * 2 + head], a1 = as1[s1 * 2 + head];
        float a2 = as1[s2 * 2 + head], a3 = as1[s3 * 2 + head];
        float g0 = h1[(size_t)s0 * 64 + lane];
        float g1 = h1[(size_t)s1 * 64 + lane];
        float g2 = h1[(size_t)s2 * 64 + lane];
        float g3 = h1[(size_t)s3 * 64 + lane];
        float w0 = __expf(lrelu_f(a0 + adn));
        float w1 = __expf(lrelu_f(a1 + adn));
        float w2 = __expf(lrelu_f(a2 + adn));
        float w3 = __expf(lrelu_f(a3 + adn));
        den += (w0 + w1) + (w2 + w3);
        acc += w0 * g0 + w1 * g1 + w2 * g2 + w3 * g3;
    }
    for (; i < endp; ++i) {
        int s0 = srclist[i];
        float w0 = __expf(lrelu_f(as1[s0 * 2 + head] + adn));
        den += w0;
        acc += w0 * h1[(size_t)s0 * 64 + lane];
    }

    float v = acc / den + b1[lane];
    h1e[(size_t)n * 64 + lane] = elu_f(v);
}

// ---------------------------------------------------------------------------
// GEMM2: h2 = h1e @ W2 ([N,64] x [64,32]) with fused alpha2 reductions
// ---------------------------------------------------------------------------
__global__ __launch_bounds__(256) void gemm2_kernel(
    const float* __restrict__ xin, const float* __restrict__ W,
    const float* __restrict__ a_src, const float* __restrict__ a_dst,
    float* __restrict__ h2, float* __restrict__ as2, float* __restrict__ ad2,
    int N)
{
    __shared__ float Wl[64 * 32];
    __shared__ float Xl[8][64];
    int tid = threadIdx.x;
    for (int i = tid; i < 64 * 32; i += 256) Wl[i] = W[i];
    int base = blockIdx.x * 8;
    for (int i = tid; i < 8 * 64; i += 256) {
        int rr = i >> 6, cc = i & 63;
        if (base + rr < N) Xl[rr][cc] = xin[(size_t)(base + rr) * 64 + cc];
    }
    __syncthreads();
    int r   = tid >> 5;
    int col = tid & 31;
    int row = base + r;
    if (row >= N) return;

    float acc = 0.f;
#pragma unroll
    for (int k = 0; k < 64; ++k) acc += Xl[r][k] * Wl[k * 32 + col];
    h2[(size_t)row * 32 + col] = acc;

    float ps = acc * a_src[col];
    float pd = acc * a_dst[col];
#pragma unroll
    for (int off = 16; off; off >>= 1) {
        ps += __shfl_xor(ps, off, 32);
        pd += __shfl_xor(pd, off, 32);
    }
    if (col == 0) { as2[row] = ps; ad2[row] = pd; }
}

// ---------------------------------------------------------------------------
// Layer-2 aggregation, gather-side: 32 lanes per dst node, 4x unrolled.
// out layout: [0,N) scores, [N, N+N*32) h
// ---------------------------------------------------------------------------
__global__ __launch_bounds__(256) void agg2_kernel(
    const int* __restrict__ rowptr, const int* __restrict__ srclist,
    const float* __restrict__ h2, const float* __restrict__ as2,
    const float* __restrict__ ad2, const float* __restrict__ b2,
    const float* __restrict__ fcW, const float* __restrict__ fcb,
    float* __restrict__ out, int N)
{
    int g = blockIdx.x * 256 + threadIdx.x;
    int n = g >> 5;
    int lane = g & 31;
    if (n >= N) return;
    float adn = ad2[n];

    float w = __expf(lrelu_f(as2[n] + adn));
    float den = w;
    float acc = w * h2[(size_t)n * 32 + lane];

    int i = rowptr[n], endp = rowptr[n + 1];
    for (; i + 3 < endp; i += 4) {
        int s0 = srclist[i], s1 = srclist[i + 1];
        int s2 = srclist[i + 2], s3 = srclist[i + 3];
        float a0 = as2[s0], a1 = as2[s1], a2 = as2[s2], a3 = as2[s3];
        float g0 = h2[(size_t)s0 * 32 + lane];
        float g1 = h2[(size_t)s1 * 32 + lane];
        float g2 = h2[(size_t)s2 * 32 + lane];
        float g3 = h2[(size_t)s3 * 32 + lane];
        float w0 = __expf(lrelu_f(a0 + adn));
        float w1 = __expf(lrelu_f(a1 + adn));
        float w2 = __expf(lrelu_f(a2 + adn));
        float w3 = __expf(lrelu_f(a3 + adn));
        den += (w0 + w1) + (w2 + w3);
        acc += w0 * g0 + w1 * g1 + w2 * g2 + w3 * g3;
    }
    for (; i < endp; ++i) {
        int s0 = srclist[i];
        float w0 = __expf(lrelu_f(as2[s0] + adn));
        den += w0;
        acc += w0 * h2[(size_t)s0 * 32 + lane];
    }

    float v = elu_f(acc / den + b2[lane]);
    out[(size_t)N + (size_t)n * 32 + lane] = v;
    float p = v * fcW[lane];
#pragma unroll
    for (int off = 16; off; off >>= 1) p += __shfl_xor(p, off, 32);
    if (lane == 0) out[n] = p + fcb[0];
}

extern "C" void kernel_launch(void* const* d_in, const int* in_sizes, int n_in,
                              void* d_out, int out_size, void* d_ws, size_t ws_size,
                              hipStream_t stream) {
    const float* x    = (const float*)d_in[0];
    const int*   ei   = (const int*)d_in[1];
    const float* W1   = (const float*)d_in[2];
    const float* a_s1 = (const float*)d_in[3];
    const float* a_d1 = (const float*)d_in[4];
    const float* b1   = (const float*)d_in[5];
    const float* W2   = (const float*)d_in[6];
    const float* a_s2 = (const float*)d_in[7];
    const float* a_d2 = (const float*)d_in[8];
    const float* b2   = (const float*)d_in[9];
    const float* fcW  = (const float*)d_in[10];
    const float* fcb  = (const float*)d_in[11];

    const int N = in_sizes[0] / 64;
    const int E = in_sizes[1] / 2;

    float* fws  = (float*)d_ws;
    float* h1   = fws;                      // N*64  (reused as h2 after agg1)
    float* h1e  = h1   + (size_t)N * 64;    // N*64
    float* as1  = h1e  + (size_t)N * 64;    // N*2
    float* ad1  = as1  + (size_t)N * 2;     // N*2
    float* as2  = ad1  + (size_t)N * 2;     // N
    float* ad2  = as2  + (size_t)N;         // N
    int*   cnt     = (int*)(ad2 + (size_t)N);  // N   (histogram, then cursor)
    int*   rowptr  = cnt + N;                  // N+1
    int*   srclist = rowptr + N + 1;           // E
    float* h2   = h1;                      // alias: h1 dead after agg1

    hipMemsetAsync(cnt, 0, sizeof(int) * (size_t)N, stream);

    hist_kernel<<<(E + 255) / 256, 256, 0, stream>>>(ei, cnt, E);
    scan_kernel<<<1, 1024, 0, stream>>>(cnt, rowptr, N);

    const int nChunks = 256;  // 256 chunks x 8 ranges = 2048 blocks
    scatter_kernel<<<nChunks * NRANGE, 256, 0, stream>>>(ei, cnt, srclist, E, N, nChunks);

    gemm1_kernel<<<(N + 3) / 4, 256, 0, stream>>>(x, W1, a_s1, a_d1, h1, as1, ad1, N);

    agg1_kernel<<<((size_t)N * 64 + 255) / 256, 256, 0, stream>>>(
        rowptr, srclist, h1, as1, ad1, b1, h1e, N);

    gemm2_kernel<<<(N + 7) / 8, 256, 0, stream>>>(h1e, W2, a_s2, a_d2, h2, as2, ad2, N);

    agg2_kernel<<<((size_t)N * 32 + 255) / 256, 256, 0, stream>>>(
        rowptr, srclist, h2, as2, ad2, b2, fcW, fcb, (float*)d_out, N);
}

// Round 4
// 394.087 us; speedup vs baseline: 2.1084x; 1.2500x over previous
//
#include <hip/hip_runtime.h>

#define NEG_SLOPE 0.2f
#define NRANGE 8          // dst-range partitions == XCD count (b%8 heuristic)
#define SCAN_TILE 2048    // elements per scan block

__device__ __forceinline__ float elu_f(float x) {
    return x > 0.f ? x : __expf(x) - 1.f;
}
__device__ __forceinline__ float lrelu_f(float x) {
    return x > 0.f ? x : NEG_SLOPE * x;
}

// ---------------------------------------------------------------------------
// CSR build step 1: histogram of destination nodes (real edges only).
// ---------------------------------------------------------------------------
__global__ __launch_bounds__(256) void hist_kernel(
    const int* __restrict__ ei, int* __restrict__ cnt, int E)
{
    int t = blockIdx.x * 256 + threadIdx.x;
    if (t < E) atomicAdd(&cnt[__builtin_nontemporal_load(&ei[E + t])], 1);
}

// ---------------------------------------------------------------------------
// Hierarchical scan phase A: per-tile sums (coalesced reads + block reduce).
// ---------------------------------------------------------------------------
__global__ __launch_bounds__(256) void scan_partial_kernel(
    const int* __restrict__ cnt, int* __restrict__ blocksum, int N)
{
    __shared__ int red[256];
    int base = blockIdx.x * SCAN_TILE;
    int s = 0;
#pragma unroll
    for (int k = 0; k < 8; ++k) {
        int i = base + k * 256 + threadIdx.x;
        if (i < N) s += cnt[i];
    }
    red[threadIdx.x] = s;
    __syncthreads();
    for (int off = 128; off; off >>= 1) {
        if (threadIdx.x < off) red[threadIdx.x] += red[threadIdx.x + off];
        __syncthreads();
    }
    if (threadIdx.x == 0) blocksum[blockIdx.x] = red[0];
}

// ---------------------------------------------------------------------------
// Hierarchical scan phase B: exclusive scan of tile sums (nb <= 1024),
// one tiny block; also writes rowptr[N] = E.
// ---------------------------------------------------------------------------
__global__ __launch_bounds__(1024) void scan_blocksum_kernel(
    int* __restrict__ blocksum, int nb, int* __restrict__ rowptr, int N, int E)
{
    __shared__ int part[1024];
    int t = threadIdx.x;
    part[t] = (t < nb) ? blocksum[t] : 0;
    __syncthreads();
    for (int off = 1; off < 1024; off <<= 1) {
        int v = (t >= off) ? part[t - off] : 0;
        __syncthreads();
        part[t] += v;
        __syncthreads();
    }
    if (t < nb) blocksum[t] = (t == 0) ? 0 : part[t - 1];  // exclusive
    if (t == 0) rowptr[N] = E;
}

// ---------------------------------------------------------------------------
// Hierarchical scan phase C: block-local exclusive scan of each tile + tile
// offset; writes rowptr and scatter cursor (cursor aliases cnt: each block
// reads its own tile before overwriting, tiles are disjoint).
// ---------------------------------------------------------------------------
__global__ __launch_bounds__(256) void scan_final_kernel(
    int* __restrict__ cnt, const int* __restrict__ blocksum,
    int* __restrict__ rowptr, int N)
{
    __shared__ int lds[SCAN_TILE];
    __shared__ int tsum[256];
    int base = blockIdx.x * SCAN_TILE;
    int tid = threadIdx.x;
#pragma unroll
    for (int k = 0; k < 8; ++k) {
        int i = base + k * 256 + tid;
        lds[k * 256 + tid] = (i < N) ? cnt[i] : 0;
    }
    __syncthreads();
    int my[8];
    int s = 0;
#pragma unroll
    for (int j = 0; j < 8; ++j) { my[j] = s; s += lds[tid * 8 + j]; }
    tsum[tid] = s;
    __syncthreads();
    for (int off = 1; off < 256; off <<= 1) {
        int v = (tid >= off) ? tsum[tid - off] : 0;
        __syncthreads();
        tsum[tid] += v;
        __syncthreads();
    }
    int texcl = (tid == 0) ? 0 : tsum[tid - 1];
    int boff = blocksum[blockIdx.x];
    __syncthreads();
#pragma unroll
    for (int j = 0; j < 8; ++j) lds[tid * 8 + j] = boff + texcl + my[j];
    __syncthreads();
#pragma unroll
    for (int k = 0; k < 8; ++k) {
        int i = base + k * 256 + tid;
        if (i < N) {
            int v = lds[k * 256 + tid];
            rowptr[i] = v;
            cnt[i] = v;      // scatter cursor
        }
    }
}

// ---------------------------------------------------------------------------
// CSR build step 3: scatter src indices grouped by dst (XCD-range-affine).
// ---------------------------------------------------------------------------
__global__ __launch_bounds__(256) void scatter_kernel(
    const int* __restrict__ ei, int* __restrict__ cursor,
    int* __restrict__ srclist, int E, int N, int nChunks)
{
    int b = blockIdx.x;
    int range = b & (NRANGE - 1);
    int chunk = b >> 3;
    int RS = (N + NRANGE - 1) / NRANGE;
    int lo = range * RS;
    int hi = lo + RS; if (hi > N) hi = N;
    int per = (E + nChunks - 1) / nChunks;
    int beg = chunk * per;
    int end = beg + per; if (end > E) end = E;
    for (int i = beg + (int)threadIdx.x; i < end; i += 256) {
        int dst = __builtin_nontemporal_load(&ei[E + i]);
        if (dst >= lo && dst < hi) {
            int src = __builtin_nontemporal_load(&ei[i]);
            int pos = atomicAdd(&cursor[dst], 1);
            srclist[pos] = src;
        }
    }
}

// ---------------------------------------------------------------------------
// GEMM1: h1 = x @ W1  ([N,64] x [64,64]) with fused alpha_src1/alpha_dst1
// ---------------------------------------------------------------------------
__global__ __launch_bounds__(256) void gemm1_kernel(
    const float* __restrict__ x, const float* __restrict__ W,
    const float* __restrict__ a_src, const float* __restrict__ a_dst,
    float* __restrict__ h1, float* __restrict__ as1, float* __restrict__ ad1,
    int N)
{
    __shared__ float Wl[64 * 64];
    __shared__ float Xl[4][64];
    int tid = threadIdx.x;
    for (int i = tid; i < 64 * 64; i += 256) Wl[i] = W[i];
    int r   = tid >> 6;
    int col = tid & 63;
    int row = blockIdx.x * 4 + r;
    if (row < N) Xl[r][col] = x[(size_t)row * 64 + col];
    __syncthreads();
    if (row >= N) return;

    float acc = 0.f;
#pragma unroll
    for (int k = 0; k < 64; ++k) acc += Xl[r][k] * Wl[k * 64 + col];
    h1[(size_t)row * 64 + col] = acc;

    int head = col >> 5;
    float ps = acc * a_src[col];
    float pd = acc * a_dst[col];
#pragma unroll
    for (int off = 16; off; off >>= 1) {
        ps += __shfl_xor(ps, off, 32);
        pd += __shfl_xor(pd, off, 32);
    }
    if ((col & 31) == 0) {
        as1[row * 2 + head] = ps;
        ad1[row * 2 + head] = pd;
    }
}

// ---------------------------------------------------------------------------
// Layer-1 aggregation, gather-side: one 64-lane wave per dst node.
// ---------------------------------------------------------------------------
__global__ __launch_bounds__(256) void agg1_kernel(
    const int* __restrict__ rowptr, const int* __restrict__ srclist,
    const float* __restrict__ h1, const float* __restrict__ as1,
    const float* __restrict__ ad1, const float* __restrict__ b1,
    float* __restrict__ h1e, int N)
{
    int n = (blockIdx.x * 256 + threadIdx.x) >> 6;
    int lane = threadIdx.x & 63;
    if (n >= N) return;
    int head = lane >> 5;
    float adn = ad1[n * 2 + head];

    float w = __expf(lrelu_f(as1[n * 2 + head] + adn));
    float den = w;
    float acc = w * h1[(size_t)n * 64 + lane];

    int i = rowptr[n], endp = rowptr[n + 1];
    for (; i + 3 < endp; i += 4) {
        int s0 = srclist[i], s1 = srclist[i + 1];
        int s2 = srclist[i + 2], s3 = srclist[i + 3];
        float a0 = as1[s0 * 2 + head], a1 = as1[s1 * 2 + head];
        float a2 = as1[s2 * 2 + head], a3 = as1[s3 * 2 + head];
        float g0 = h1[(size_t)s0 * 64 + lane];
        float g1 = h1[(size_t)s1 * 64 + lane];
        float g2 = h1[(size_t)s2 * 64 + lane];
        float g3 = h1[(size_t)s3 * 64 + lane];
        float w0 = __expf(lrelu_f(a0 + adn));
        float w1 = __expf(lrelu_f(a1 + adn));
        float w2 = __expf(lrelu_f(a2 + adn));
        float w3 = __expf(lrelu_f(a3 + adn));
        den += (w0 + w1) + (w2 + w3);
        acc += w0 * g0 + w1 * g1 + w2 * g2 + w3 * g3;
    }
    for (; i < endp; ++i) {
        int s0 = srclist[i];
        float w0 = __expf(lrelu_f(as1[s0 * 2 + head] + adn));
        den += w0;
        acc += w0 * h1[(size_t)s0 * 64 + lane];
    }

    float v = acc / den + b1[lane];
    h1e[(size_t)n * 64 + lane] = elu_f(v);
}

// ---------------------------------------------------------------------------
// GEMM2: h2 = h1e @ W2 ([N,64] x [64,32]) with fused alpha2 reductions
// ---------------------------------------------------------------------------
__global__ __launch_bounds__(256) void gemm2_kernel(
    const float* __restrict__ xin, const float* __restrict__ W,
    const float* __restrict__ a_src, const float* __restrict__ a_dst,
    float* __restrict__ h2, float* __restrict__ as2, float* __restrict__ ad2,
    int N)
{
    __shared__ float Wl[64 * 32];
    __shared__ float Xl[8][64];
    int tid = threadIdx.x;
    for (int i = tid; i < 64 * 32; i += 256) Wl[i] = W[i];
    int base = blockIdx.x * 8;
    for (int i = tid; i < 8 * 64; i += 256) {
        int rr = i >> 6, cc = i & 63;
        if (base + rr < N) Xl[rr][cc] = xin[(size_t)(base + rr) * 64 + cc];
    }
    __syncthreads();
    int r   = tid >> 5;
    int col = tid & 31;
    int row = base + r;
    if (row >= N) return;

    float acc = 0.f;
#pragma unroll
    for (int k = 0; k < 64; ++k) acc += Xl[r][k] * Wl[k * 32 + col];
    h2[(size_t)row * 32 + col] = acc;

    float ps = acc * a_src[col];
    float pd = acc * a_dst[col];
#pragma unroll
    for (int off = 16; off; off >>= 1) {
        ps += __shfl_xor(ps, off, 32);
        pd += __shfl_xor(pd, off, 32);
    }
    if (col == 0) { as2[row] = ps; ad2[row] = pd; }
}

// ---------------------------------------------------------------------------
// Layer-2 aggregation, gather-side: 32 lanes per dst node, 4x unrolled.
// out layout: [0,N) scores, [N, N+N*32) h
// ---------------------------------------------------------------------------
__global__ __launch_bounds__(256) void agg2_kernel(
    const int* __restrict__ rowptr, const int* __restrict__ srclist,
    const float* __restrict__ h2, const float* __restrict__ as2,
    const float* __restrict__ ad2, const float* __restrict__ b2,
    const float* __restrict__ fcW, const float* __restrict__ fcb,
    float* __restrict__ out, int N)
{
    int g = blockIdx.x * 256 + threadIdx.x;
    int n = g >> 5;
    int lane = g & 31;
    if (n >= N) return;
    float adn = ad2[n];

    float w = __expf(lrelu_f(as2[n] + adn));
    float den = w;
    float acc = w * h2[(size_t)n * 32 + lane];

    int i = rowptr[n], endp = rowptr[n + 1];
    for (; i + 3 < endp; i += 4) {
        int s0 = srclist[i], s1 = srclist[i + 1];
        int s2 = srclist[i + 2], s3 = srclist[i + 3];
        float a0 = as2[s0], a1 = as2[s1], a2 = as2[s2], a3 = as2[s3];
        float g0 = h2[(size_t)s0 * 32 + lane];
        float g1 = h2[(size_t)s1 * 32 + lane];
        float g2 = h2[(size_t)s2 * 32 + lane];
        float g3 = h2[(size_t)s3 * 32 + lane];
        float w0 = __expf(lrelu_f(a0 + adn));
        float w1 = __expf(lrelu_f(a1 + adn));
        float w2 = __expf(lrelu_f(a2 + adn));
        float w3 = __expf(lrelu_f(a3 + adn));
        den += (w0 + w1) + (w2 + w3);
        acc += w0 * g0 + w1 * g1 + w2 * g2 + w3 * g3;
    }
    for (; i < endp; ++i) {
        int s0 = srclist[i];
        float w0 = __expf(lrelu_f(as2[s0] + adn));
        den += w0;
        acc += w0 * h2[(size_t)s0 * 32 + lane];
    }

    float v = elu_f(acc / den + b2[lane]);
    out[(size_t)N + (size_t)n * 32 + lane] = v;
    float p = v * fcW[lane];
#pragma unroll
    for (int off = 16; off; off >>= 1) p += __shfl_xor(p, off, 32);
    if (lane == 0) out[n] = p + fcb[0];
}

extern "C" void kernel_launch(void* const* d_in, const int* in_sizes, int n_in,
                              void* d_out, int out_size, void* d_ws, size_t ws_size,
                              hipStream_t stream) {
    const float* x    = (const float*)d_in[0];
    const int*   ei   = (const int*)d_in[1];
    const float* W1   = (const float*)d_in[2];
    const float* a_s1 = (const float*)d_in[3];
    const float* a_d1 = (const float*)d_in[4];
    const float* b1   = (const float*)d_in[5];
    const float* W2   = (const float*)d_in[6];
    const float* a_s2 = (const float*)d_in[7];
    const float* a_d2 = (const float*)d_in[8];
    const float* b2   = (const float*)d_in[9];
    const float* fcW  = (const float*)d_in[10];
    const float* fcb  = (const float*)d_in[11];

    const int N = in_sizes[0] / 64;
    const int E = in_sizes[1] / 2;

    float* fws  = (float*)d_ws;
    float* h1   = fws;                      // N*64  (reused as h2 after agg1)
    float* h1e  = h1   + (size_t)N * 64;    // N*64
    float* as1  = h1e  + (size_t)N * 64;    // N*2
    float* ad1  = as1  + (size_t)N * 2;     // N*2
    float* as2  = ad1  + (size_t)N * 2;     // N
    float* ad2  = as2  + (size_t)N;         // N
    int*   cnt     = (int*)(ad2 + (size_t)N);  // N   (histogram, then cursor)
    int*   rowptr  = cnt + N;                  // N+1
    int*   srclist = rowptr + N + 1;           // E
    int*   blocksum = srclist + E;             // ceil(N/SCAN_TILE)
    float* h2   = h1;                      // alias: h1 dead after agg1

    const int nScan = (N + SCAN_TILE - 1) / SCAN_TILE;

    hipMemsetAsync(cnt, 0, sizeof(int) * (size_t)N, stream);

    hist_kernel<<<(E + 255) / 256, 256, 0, stream>>>(ei, cnt, E);

    scan_partial_kernel<<<nScan, 256, 0, stream>>>(cnt, blocksum, N);
    scan_blocksum_kernel<<<1, 1024, 0, stream>>>(blocksum, nScan, rowptr, N, E);
    scan_final_kernel<<<nScan, 256, 0, stream>>>(cnt, blocksum, rowptr, N);

    const int nChunks = 256;  // 256 chunks x 8 ranges = 2048 blocks
    scatter_kernel<<<nChunks * NRANGE, 256, 0, stream>>>(ei, cnt, srclist, E, N, nChunks);

    gemm1_kernel<<<(N + 3) / 4, 256, 0, stream>>>(x, W1, a_s1, a_d1, h1, as1, ad1, N);

    agg1_kernel<<<((size_t)N * 64 + 255) / 256, 256, 0, stream>>>(
        rowptr, srclist, h1, as1, ad1, b1, h1e, N);

    gemm2_kernel<<<(N + 7) / 8, 256, 0, stream>>>(h1e, W2, a_s2, a_d2, h2, as2, ad2, N);

    agg2_kernel<<<((size_t)N * 32 + 255) / 256, 256, 0, stream>>>(
        rowptr, srclist, h2, as2, ad2, b2, fcW, fcb, (float*)d_out, N);
}